// Round 11
// baseline (247.948 us; speedup 1.0000x reference)
//
#include <hip/hip_runtime.h>

typedef unsigned short u16;
typedef unsigned int   u32;
typedef short bf16x8 __attribute__((ext_vector_type(8)));
typedef float f32x4  __attribute__((ext_vector_type(4)));
typedef float f32x2  __attribute__((ext_vector_type(2)));

#define B_   8
#define C_   128
#define H_   128
#define W_   128
#define NH   4
#define D_   32
#define HW_  16384
#define SCALE 0.17677669529663687f
#define SCL2E 0.2550437602866803f   // SCALE * log2(e)

__device__ __forceinline__ float bf2f_u(u16 u) { union { u32 i; float f; } x; x.i = ((u32)u) << 16; return x.f; }
__device__ __forceinline__ float bflo(u32 u)   { union { u32 i; float f; } x; x.i = u << 16; return x.f; }
__device__ __forceinline__ float bfhi(u32 u)   { union { u32 i; float f; } x; x.i = u & 0xffff0000u; return x.f; }
__device__ __forceinline__ u16   f2bf(float f) {
  union { float f; u32 i; } x; x.f = f;
  u32 i = x.i;
  return (u16)((i + 0x7fffu + ((i >> 16) & 1u)) >> 16);
}
__device__ __forceinline__ u32 pk2(float a, float b) {
  return (u32)f2bf(a) | ((u32)f2bf(b) << 16);
}
__device__ __forceinline__ u32 cvtpk(float a, float b) {
  u32 r;
  asm("v_cvt_pk_bf16_f32 %0, %1, %2" : "=v"(r) : "v"(a), "v"(b));
  return r;
}
__device__ __forceinline__ bf16x8 ld_frag_g(const u16* p) {
  union { uint4 u; bf16x8 f; } c; c.u = *(const uint4*)p; return c.f;
}

// ---------------------------------------------------------------------------
// k_wcvt2: convert both weight tensors f32 -> bf16 in one launch.
// ---------------------------------------------------------------------------
__global__ __launch_bounds__(256) void k_wcvt2(const float* __restrict__ wq,
                                               const float* __restrict__ wp,
                                               u16* __restrict__ dq,
                                               u16* __restrict__ dp) {
  int i = blockIdx.x * 256 + threadIdx.x;
  const float* src; u16* dst; int j;
  if (i < 12288) { src = wq; dst = dq; j = i; }
  else           { src = wp; dst = dp; j = i - 12288; }
  float4 v = ((const float4*)src)[j];
  uint2 st; st.x = pk2(v.x, v.y); st.y = pk2(v.z, v.w);
  *(uint2*)(dst + (size_t)j * 4) = st;
}

// ---------------------------------------------------------------------------
// k_qkv R12 (unchanged, champion): LDS weight staging + coalesced epilogue.
// ---------------------------------------------------------------------------
__global__ __launch_bounds__(256) void k_qkv(const float* __restrict__ x,
                                             const u16* __restrict__ wqb,
                                             u16* __restrict__ qkvb) {
  __shared__ u32 tile[8704];   // max(x-stage 128*65, weights 128*68)
  const int tid = threadIdx.x, w = tid >> 6, lane = tid & 63;
  const int c16 = lane & 15, rg = lane >> 4;
  const int b = blockIdx.z;
  const int P0 = blockIdx.x * 128;
  const float* sb = x + (size_t)b * C_ * HW_ + P0;

  #pragma unroll
  for (int ci = 0; ci < 4; ++ci) {
    int cp = 16 * w + 4 * ci + rg;
    #pragma unroll
    for (int ph = 0; ph < 2; ++ph) {
      int p = 4 * c16 + 64 * ph;
      const float* r0 = sb + (size_t)(2 * cp) * HW_ + p;
      float4 a  = *(const float4*)r0;
      float4 bb = *(const float4*)(r0 + HW_);
      tile[(p + 0) * 65 + cp] = pk2(a.x, bb.x);
      tile[(p + 1) * 65 + cp] = pk2(a.y, bb.y);
      tile[(p + 2) * 65 + cp] = pk2(a.z, bb.z);
      tile[(p + 3) * 65 + cp] = pk2(a.w, bb.w);
    }
  }
  __syncthreads();

  const int pw = w * 32;
  bf16x8 bfr[2][4];
  #pragma unroll
  for (int nt = 0; nt < 2; ++nt)
    #pragma unroll
    for (int kk = 0; kk < 4; ++kk) {
      int p = pw + nt * 16 + c16;
      int cp0 = kk * 16 + rg * 4;
      union { u32 d[4]; bf16x8 f; } u;
      u.d[0] = tile[p * 65 + cp0];
      u.d[1] = tile[p * 65 + cp0 + 1];
      u.d[2] = tile[p * 65 + cp0 + 2];
      u.d[3] = tile[p * 65 + cp0 + 3];
      bfr[nt][kk] = u.f;
    }
  __syncthreads();   // x-tile dead; region reused for weights + eb

  u32* eb = tile + w * 544;

  const int p0 = P0 + pw;
  const f32x4 zero = {0.f, 0.f, 0.f, 0.f};
  #pragma unroll 1
  for (int pass = 0; pass < 3; ++pass) {
    {
      const u16* wsrc = wqb + (size_t)pass * 16384;
      #pragma unroll
      for (int j = 0; j < 8; ++j) {
        int idx = tid + 256 * j;
        uint4 v = *(const uint4*)(wsrc + idx * 8);
        *(uint4*)(tile + (idx >> 4) * 68 + (idx & 15) * 4) = v;
      }
    }
    __syncthreads();

    f32x4 acc[8][2];
    #pragma unroll
    for (int mt = 0; mt < 8; ++mt) { acc[mt][0] = zero; acc[mt][1] = zero; }

    #pragma unroll
    for (int kk = 0; kk < 4; ++kk) {
      #pragma unroll
      for (int mt = 0; mt < 8; ++mt) {
        union { uint4 u; bf16x8 f; } afu;
        afu.u = *(const uint4*)(tile + (mt * 16 + c16) * 68 + kk * 16 + rg * 4);
        acc[mt][0] = __builtin_amdgcn_mfma_f32_16x16x32_bf16(afu.f, bfr[0][kk], acc[mt][0], 0, 0, 0);
        acc[mt][1] = __builtin_amdgcn_mfma_f32_16x16x32_bf16(afu.f, bfr[1][kk], acc[mt][1], 0, 0, 0);
      }
    }
    __syncthreads();   // all waves' weight reads done before eb overwrites

    u16* ob = qkvb + (size_t)pass * ((size_t)B_ * NH * HW_ * D_);
    #pragma unroll
    for (int h = 0; h < 4; ++h) {
      #pragma unroll
      for (int m2 = 0; m2 < 2; ++m2) {
        #pragma unroll
        for (int nt = 0; nt < 2; ++nt) {
          f32x4 oa = acc[2 * h + m2][nt];
          int pixl = nt * 16 + c16;
          int dp = m2 * 8 + rg * 2;
          eb[pixl * 17 + dp]     = cvtpk(oa[0], oa[1]);
          eb[pixl * 17 + dp + 1] = cvtpk(oa[2], oa[3]);
        }
      }
      #pragma unroll
      for (int s = 0; s < 2; ++s) {
        int pixl = s * 16 + (lane >> 2);
        const u32* src = eb + pixl * 17 + (lane & 3) * 4;
        uint4 v; v.x = src[0]; v.y = src[1]; v.z = src[2]; v.w = src[3];
        *(uint4*)(ob + ((size_t)(b * NH + h) * HW_ + p0 + pixl) * 32 + (lane & 3) * 8) = v;
      }
    }
    __syncthreads();   // eb readbacks done before next pass's weight load
  }
}

// ---------------------------------------------------------------------------
// k_proj R12 (unchanged, champion): LDS weight staging + coalesced epilogue.
// ---------------------------------------------------------------------------
__global__ __launch_bounds__(256) void k_proj(const u16* __restrict__ cv,
                                              const u16* __restrict__ wpb,
                                              float* __restrict__ out) {
  __shared__ u32 tile[8704];
  const int tid = threadIdx.x, w = tid >> 6, lane = tid & 63;
  const int c16 = lane & 15, rg = lane >> 4;
  const int b = blockIdx.z;
  const int P0 = blockIdx.x * 128;
  const u16* sb = cv + (size_t)b * C_ * HW_ + P0;

  #pragma unroll
  for (int ci = 0; ci < 4; ++ci) {
    int cp = 16 * w + 4 * ci + rg;
    #pragma unroll
    for (int ph = 0; ph < 2; ++ph) {
      int p = 4 * c16 + 64 * ph;
      const u16* r0 = sb + (size_t)(2 * cp) * HW_ + p;
      uint2 a  = *(const uint2*)r0;
      uint2 bb = *(const uint2*)(r0 + HW_);
      tile[(p + 0) * 65 + cp] = (a.x & 0xffffu) | (bb.x << 16);
      tile[(p + 1) * 65 + cp] = (a.x >> 16)     | (bb.x & 0xffff0000u);
      tile[(p + 2) * 65 + cp] = (a.y & 0xffffu) | (bb.y << 16);
      tile[(p + 3) * 65 + cp] = (a.y >> 16)     | (bb.y & 0xffff0000u);
    }
  }
  __syncthreads();

  const int pw = w * 32;
  bf16x8 bfr[2][4];
  #pragma unroll
  for (int nt = 0; nt < 2; ++nt)
    #pragma unroll
    for (int kk = 0; kk < 4; ++kk) {
      int p = pw + nt * 16 + c16;
      int cp0 = kk * 16 + rg * 4;
      union { u32 d[4]; bf16x8 f; } u;
      u.d[0] = tile[p * 65 + cp0];
      u.d[1] = tile[p * 65 + cp0 + 1];
      u.d[2] = tile[p * 65 + cp0 + 2];
      u.d[3] = tile[p * 65 + cp0 + 3];
      bfr[nt][kk] = u.f;
    }
  __syncthreads();   // tile dead; reuse for weights + eb

  u32* eb = tile + w * 544;

  #pragma unroll
  for (int j = 0; j < 8; ++j) {
    int idx = tid + 256 * j;
    uint4 v = *(const uint4*)(wpb + idx * 8);
    *(uint4*)(tile + (idx >> 4) * 68 + (idx & 15) * 4) = v;
  }
  __syncthreads();

  const int p0 = P0 + pw;
  const f32x4 zero = {0.f, 0.f, 0.f, 0.f};
  f32x4 acc[8][2];
  #pragma unroll
  for (int mt = 0; mt < 8; ++mt) { acc[mt][0] = zero; acc[mt][1] = zero; }

  #pragma unroll
  for (int kk = 0; kk < 4; ++kk) {
    #pragma unroll
    for (int mt = 0; mt < 8; ++mt) {
      union { uint4 u; bf16x8 f; } afu;
      afu.u = *(const uint4*)(tile + (mt * 16 + c16) * 68 + kk * 16 + rg * 4);
      acc[mt][0] = __builtin_amdgcn_mfma_f32_16x16x32_bf16(afu.f, bfr[0][kk], acc[mt][0], 0, 0, 0);
      acc[mt][1] = __builtin_amdgcn_mfma_f32_16x16x32_bf16(afu.f, bfr[1][kk], acc[mt][1], 0, 0, 0);
    }
  }
  __syncthreads();   // weight reads done before eb overwrites

  float* ob = out + (size_t)b * C_ * HW_;
  #pragma unroll
  for (int mt = 0; mt < 8; ++mt) {
    #pragma unroll
    for (int nt = 0; nt < 2; ++nt) {
      f32x4 oa = acc[mt][nt];
      int pixl = nt * 16 + c16;
      #pragma unroll
      for (int r = 0; r < 4; ++r) {
        union { float f; u32 u; } cu; cu.f = oa[r];
        eb[(rg * 4 + r) * 33 + pixl] = cu.u;
      }
    }
    #pragma unroll
    for (int s = 0; s < 2; ++s) {
      int ol = s * 8 + (lane >> 3);
      int px = (lane & 7) * 4;
      const u32* src = eb + ol * 33 + px;
      uint4 v; v.x = src[0]; v.y = src[1]; v.z = src[2]; v.w = src[3];
      *(uint4*)(ob + (size_t)(mt * 16 + ol) * HW_ + p0 + px) = v;
    }
  }
}

// ---------------------------------------------------------------------------
// k_attn_mfma R15: R13 ordering restored (R14's pipeline regressed: PV's
// ds_reads wait for P ds_writes regardless, and +12 VGPR cut occupancy).
// New: decay chain-break — Rn[nt] = {e^(-16g nt), e^(+16g nt)} precomputed,
// each nt-group starts at F2*linv*Rn[nt]: 8 independent 4-step chains
// instead of one serial 32-step pk_mul chain (~128 cy/mt of pure stall).
// ---------------------------------------------------------------------------
__global__ __launch_bounds__(256) void k_attn_mfma(const u16* __restrict__ qb,
                                                   const u16* __restrict__ kb,
                                                   const u16* __restrict__ vb,
                                                   const float* __restrict__ gp,
                                                   u16* __restrict__ houtb,
                                                   u16* __restrict__ woutb) {
  __shared__ u32 lds[4][16 * 68 + 32 * 18];
  const int tid  = threadIdx.x;
  const int w    = tid >> 6;
  const int lane = tid & 63;
  const int head = blockIdx.y & 3;
  const int axis = blockIdx.y >> 2;
  const int b    = blockIdx.z;
  const int line = blockIdx.x * 4 + w;
  u32* vt = &lds[w][0];
  u32* pt = &lds[w][0];          // alias: vt dead after vf frags resident
  u32* ot = &lds[w][16 * 68];    // output staging tile [32 d][18 dw]
  const size_t base = (size_t)(b * NH + head) * HW_ * D_;
  const float g = gp[0];
  const int c16 = lane & 15, rg = lane >> 4;
  const size_t pstride = axis ? (size_t)128 * D_ : (size_t)D_;
  const size_t lbase   = base + (size_t)line * (axis ? D_ : 128 * D_);

  u32 v0r[16], v1r[16];
  {
    const u16* v0p = vb + lbase + (size_t)(2 * lane) * pstride;
    const u16* v1p = v0p + pstride;
    #pragma unroll
    for (int t = 0; t < 4; ++t) {
      *(uint4*)&v0r[4 * t] = *(const uint4*)(v0p + 8 * t);
      *(uint4*)&v1r[4 * t] = *(const uint4*)(v1p + 8 * t);
    }
  }

  bf16x8 kf[8];
  #pragma unroll
  for (int nt = 0; nt < 8; ++nt)
    kf[nt] = ld_frag_g(kb + lbase + (size_t)(nt * 16 + c16) * pstride + rg * 8);

  bf16x8 vf[2][4];
  #pragma unroll
  for (int ph = 0; ph < 2; ++ph) {
    #pragma unroll
    for (int dw = 0; dw < 8; ++dw) {
      u32 a = v0r[ph * 8 + dw], bq = v1r[ph * 8 + dw];
      u32 lo = (a & 0xffffu) | (bq << 16);
      u32 hi = (a >> 16) | (bq & 0xffff0000u);
      vt[(2 * dw) * 68 + lane]     = lo;
      vt[(2 * dw + 1) * 68 + lane] = hi;
    }
    #pragma unroll
    for (int t = 0; t < 4; ++t) {
      union { uint4 u; bf16x8 f; } c;
      c.u = *(const uint4*)(vt + c16 * 68 + t * 16 + rg * 4);
      vf[ph][t] = c.f;
    }
  }

  const float R1v  = __expf(-g),        Ri1v  = __expf(g);
  const float R16v = __expf(-16.f * g), Ri16v = __expf(16.f * g);
  const f32x2 R1p   = {R1v,  Ri1v};
  const f32x2 R16p  = {R16v, Ri16v};
  const f32x2 R16ip = {Ri16v, R16v};
  float t0 = (float)(rg * 4 - c16);
  f32x2 F2 = {__expf(-g * t0), __expf(g * t0)};
  // chain-break: per-nt starting factors, independent chains
  f32x2 Rn[8];
  Rn[0] = (f32x2){1.f, 1.f};
  #pragma unroll
  for (int nt = 1; nt < 8; ++nt) Rn[nt] = Rn[nt - 1] * R16p;

  u16* ob = axis ? woutb : houtb;
  const f32x4 zero = {0.f, 0.f, 0.f, 0.f};

  bf16x8 qf = ld_frag_g(qb + lbase + (size_t)c16 * pstride + rg * 8);

  #pragma unroll 1
  for (int mt = 0; mt < 8; ++mt) {
    int mtn = mt < 7 ? mt + 1 : 7;
    bf16x8 qf_n = ld_frag_g(qb + lbase + (size_t)(mtn * 16 + c16) * pstride + rg * 8);

    f32x4 sa[8];
    __builtin_amdgcn_s_setprio(1);
    #pragma unroll
    for (int nt = 0; nt < 8; ++nt)
      sa[nt] = __builtin_amdgcn_mfma_f32_16x16x32_bf16(kf[nt], qf, zero, 0, 0, 0);
    __builtin_amdgcn_s_setprio(0);

    f32x2 l2 = {0.f, 0.f};
    #pragma unroll
    for (int nt = 0; nt < 8; ++nt) {
      f32x4 s4 = sa[nt] * SCL2E;
      float e0 = __builtin_amdgcn_exp2f(s4[0]);
      float e1 = __builtin_amdgcn_exp2f(s4[1]);
      float e2 = __builtin_amdgcn_exp2f(s4[2]);
      float e3 = __builtin_amdgcn_exp2f(s4[3]);
      sa[nt][0] = e0; sa[nt][1] = e1; sa[nt][2] = e2; sa[nt][3] = e3;
      l2 += (f32x2){e0, e1};
      l2 += (f32x2){e2, e3};
    }
    float l = l2[0] + l2[1];
    l += __shfl_xor(l, 16);
    l += __shfl_xor(l, 32);
    float linv = __builtin_amdgcn_rcpf(l);

    // decay * 1/l fused; 8 independent 4-step chains (WAS serial 32-step)
    f32x2 fl = F2 * linv;
    #pragma unroll
    for (int nt = 0; nt < 8; ++nt) {
      f32x2 ffi = fl * Rn[nt];
      float d0 = fminf(ffi[0], ffi[1]); ffi *= R1p;
      float d1 = fminf(ffi[0], ffi[1]); ffi *= R1p;
      float d2 = fminf(ffi[0], ffi[1]); ffi *= R1p;
      float d3 = fminf(ffi[0], ffi[1]);
      f32x2 p01 = (f32x2){sa[nt][0], sa[nt][1]} * (f32x2){d0, d1};
      f32x2 p23 = (f32x2){sa[nt][2], sa[nt][3]} * (f32x2){d2, d3};
      uint2 st;
      st.x = cvtpk(p01[0], p01[1]);
      st.y = cvtpk(p23[0], p23[1]);
      *(uint2*)(pt + c16 * 68 + nt * 8 + rg * 2) = st;
    }
    F2 *= R16ip;

    f32x4 oa0 = zero, oa1 = zero;
    __builtin_amdgcn_s_setprio(1);
    #pragma unroll
    for (int t = 0; t < 4; ++t) {
      union { uint4 u; bf16x8 f; } af;
      af.u = *(const uint4*)(pt + c16 * 68 + t * 16 + rg * 4);
      oa0 = __builtin_amdgcn_mfma_f32_16x16x32_bf16(af.f, vf[0][t], oa0, 0, 0, 0);
      oa1 = __builtin_amdgcn_mfma_f32_16x16x32_bf16(af.f, vf[1][t], oa1, 0, 0, 0);
    }
    __builtin_amdgcn_s_setprio(0);

    {
      int mo = mt & 1;
      uint2 st0, st1;
      st0.x = cvtpk(oa0[0], oa0[1]); st0.y = cvtpk(oa0[2], oa0[3]);
      st1.x = cvtpk(oa1[0], oa1[1]); st1.y = cvtpk(oa1[2], oa1[3]);
      *(uint2*)(ot + c16 * 18 + mo * 8 + rg * 2)        = st0;
      *(uint2*)(ot + (16 + c16) * 18 + mo * 8 + rg * 2) = st1;
      if (mo) {
        int zb = (mt >> 1) * 32;
        int q = lane & 3;
        #pragma unroll
        for (int s = 0; s < 2; ++s) {
          int d = s * 16 + (lane >> 2);
          const u32* src = ot + d * 18 + q * 4;
          uint4 v; v.x = src[0]; v.y = src[1]; v.z = src[2]; v.w = src[3];
          *(uint4*)(ob + ((size_t)(b * C_ + head * D_ + d) * 128 + line) * 128 + zb + q * 8) = v;
        }
      }
    }
    qf = qf_n;
  }
}

// ---------------------------------------------------------------------------
// k_conv R14 (unchanged, champion): conflict-free transpose-add + vectorized
// 8-pixel stencil with coalesced uint4 stores.
// ---------------------------------------------------------------------------
__global__ __launch_bounds__(256) void k_conv(const u16* __restrict__ hb,
                                              const u16* __restrict__ wb,
                                              const float* __restrict__ wdw,
                                              u16* __restrict__ convo) {
  __shared__ u16 t[128 * 136];
  const int tid = threadIdx.x;
  const int c = blockIdx.x, b = blockIdx.y;
  const size_t pb = (size_t)(b * C_ + c) * HW_;

  for (int i = tid; i < 2048; i += 256) {
    int e = i * 8; int r = e >> 7, col = e & 127;
    *(uint4*)&t[r * 136 + col] = *(const uint4*)(hb + pb + e);
  }
  __syncthreads();

  {
    const int p = tid & 63;
    const int hc0 = (tid >> 6) * 32;
    u32* tw = (u32*)t;
    u32 w0[16], w1[16];
    const u16* r0 = wb + pb + (size_t)(2 * p) * 128 + hc0;
    const u16* r1 = r0 + 128;
    #pragma unroll
    for (int q = 0; q < 4; ++q) {
      *(uint4*)&w0[4 * q] = *(const uint4*)(r0 + 8 * q);
      *(uint4*)&w1[4 * q] = *(const uint4*)(r1 + 8 * q);
    }
    #pragma unroll
    for (int k = 0; k < 32; ++k) {
      u32 d = tw[(hc0 + k) * 68 + p];
      u32 wa = (k & 1) ? (w0[k >> 1] & 0xffff0000u) : (w0[k >> 1] << 16);
      u32 wc = (k & 1) ? (w1[k >> 1] & 0xffff0000u) : (w1[k >> 1] << 16);
      union { u32 u; float f; } fa, fc;
      fa.u = wa; fc.u = wc;
      f32x2 s = (f32x2){bflo(d) + fa.f, bfhi(d) + fc.f};
      tw[(hc0 + k) * 68 + p] = cvtpk(s[0], s[1]);
    }
  }
  __syncthreads();

  float k9[9];
  #pragma unroll
  for (int i = 0; i < 9; ++i) k9[i] = wdw[c * 9 + i];

  for (int ch = tid; ch < 2048; ch += 256) {
    int r = ch >> 4;
    int c0 = (ch & 15) << 3;
    float a0 = 0.f, a1 = 0.f, a2 = 0.f, a3 = 0.f;
    float a4 = 0.f, a5 = 0.f, a6 = 0.f, a7 = 0.f;
    #pragma unroll
    for (int di = 0; di < 3; ++di) {
      int rr = r + di - 1;
      if (rr < 0 || rr > 127) continue;
      const u16* row = &t[rr * 136 + c0];
      union { uint4 u; u16 h[8]; } m;
      m.u = *(const uint4*)row;
      float v0 = c0 ? bf2f_u(row[-1]) : 0.f;
      float v1 = bf2f_u(m.h[0]), v2 = bf2f_u(m.h[1]), v3 = bf2f_u(m.h[2]);
      float v4 = bf2f_u(m.h[3]), v5 = bf2f_u(m.h[4]), v6 = bf2f_u(m.h[5]);
      float v7 = bf2f_u(m.h[6]), v8 = bf2f_u(m.h[7]);
      float v9 = (c0 < 120) ? bf2f_u(row[8]) : 0.f;
      float ka = k9[di * 3], kb2 = k9[di * 3 + 1], kc = k9[di * 3 + 2];
      a0 += ka * v0 + kb2 * v1 + kc * v2;
      a1 += ka * v1 + kb2 * v2 + kc * v3;
      a2 += ka * v2 + kb2 * v3 + kc * v4;
      a3 += ka * v3 + kb2 * v4 + kc * v5;
      a4 += ka * v4 + kb2 * v5 + kc * v6;
      a5 += ka * v5 + kb2 * v6 + kc * v7;
      a6 += ka * v6 + kb2 * v7 + kc * v8;
      a7 += ka * v7 + kb2 * v8 + kc * v9;
    }
    uint4 st;
    st.x = cvtpk(a0, a1); st.y = cvtpk(a2, a3);
    st.z = cvtpk(a4, a5); st.w = cvtpk(a6, a7);
    *(uint4*)(convo + pb + r * 128 + c0) = st;
  }
}

// ---------------------------------------------------------------------------
extern "C" void kernel_launch(void* const* d_in, const int* in_sizes, int n_in,
                              void* d_out, int out_size, void* d_ws, size_t ws_size,
                              hipStream_t stream) {
  const float* x     = (const float*)d_in[0];
  const float* wqkv  = (const float*)d_in[1];
  const float* wproj = (const float*)d_in[2];
  const float* wdw   = (const float*)d_in[3];
  const float* gamma = (const float*)d_in[4];
  float* out = (float*)d_out;
  char* ws = (char*)d_ws;

  u16* q   = (u16*)(ws);                    // 32 MB [B,4,HW,32] bf16
  u16* k   = (u16*)(ws + 33554432ull);      // 32 MB
  u16* v   = (u16*)(ws + 67108864ull);      // 32 MB
  u16* hb  = (u16*)(ws + 100663296ull);     // 32 MB [B,C,H,W] bf16 (attn-H out)
  u16* wb  = (u16*)(ws + 134217728ull);     // 32 MB [B,C,W,H] bf16 (attn-W out)
  u16* cv  = (u16*)(ws + 167772160ull);     // 32 MB [B,C,HW] bf16 (conv out)
  u16* wqb = (u16*)(ws + 201326592ull);     // 96 KB bf16 qkv weights
  u16* wpb = (u16*)(ws + 201326592ull + 131072ull); // 32 KB bf16 proj weights

  k_wcvt2    <<<dim3(64),        256, 0, stream>>>(wqkv, wproj, wqb, wpb);
  k_qkv      <<<dim3(128, 1, 8), 256, 0, stream>>>(x, wqb, q);
  k_attn_mfma<<<dim3(32, 8, 8),  256, 0, stream>>>(q, k, v, gamma, hb, wb);
  k_conv     <<<dim3(128, 8),    256, 0, stream>>>(hb, wb, wdw, cv);
  k_proj     <<<dim3(128, 1, 8), 256, 0, stream>>>(cv, wpb, out);
}

// Round 12
// 243.205 us; speedup vs baseline: 1.0195x; 1.0195x over previous
//
#include <hip/hip_runtime.h>

typedef unsigned short u16;
typedef unsigned int   u32;
typedef short bf16x8 __attribute__((ext_vector_type(8)));
typedef float f32x4  __attribute__((ext_vector_type(4)));
typedef float f32x2  __attribute__((ext_vector_type(2)));

#define B_   8
#define C_   128
#define H_   128
#define W_   128
#define NH   4
#define D_   32
#define HW_  16384
#define SCALE 0.17677669529663687f
#define SCL2E 0.2550437602866803f   // SCALE * log2(e)

__device__ __forceinline__ float bf2f_u(u16 u) { union { u32 i; float f; } x; x.i = ((u32)u) << 16; return x.f; }
__device__ __forceinline__ float bflo(u32 u)   { union { u32 i; float f; } x; x.i = u << 16; return x.f; }
__device__ __forceinline__ float bfhi(u32 u)   { union { u32 i; float f; } x; x.i = u & 0xffff0000u; return x.f; }
__device__ __forceinline__ u16   f2bf(float f) {
  union { float f; u32 i; } x; x.f = f;
  u32 i = x.i;
  return (u16)((i + 0x7fffu + ((i >> 16) & 1u)) >> 16);
}
__device__ __forceinline__ u32 pk2(float a, float b) {
  return (u32)f2bf(a) | ((u32)f2bf(b) << 16);
}
__device__ __forceinline__ u32 cvtpk(float a, float b) {
  u32 r;
  asm("v_cvt_pk_bf16_f32 %0, %1, %2" : "=v"(r) : "v"(a), "v"(b));
  return r;
}
__device__ __forceinline__ bf16x8 ld_frag_g(const u16* p) {
  union { uint4 u; bf16x8 f; } c; c.u = *(const uint4*)p; return c.f;
}

// ---------------------------------------------------------------------------
// k_wcvt2: convert both weight tensors f32 -> bf16 in one launch.
// ---------------------------------------------------------------------------
__global__ __launch_bounds__(256) void k_wcvt2(const float* __restrict__ wq,
                                               const float* __restrict__ wp,
                                               u16* __restrict__ dq,
                                               u16* __restrict__ dp) {
  int i = blockIdx.x * 256 + threadIdx.x;
  const float* src; u16* dst; int j;
  if (i < 12288) { src = wq; dst = dq; j = i; }
  else           { src = wp; dst = dp; j = i - 12288; }
  float4 v = ((const float4*)src)[j];
  uint2 st; st.x = pk2(v.x, v.y); st.y = pk2(v.z, v.w);
  *(uint2*)(dst + (size_t)j * 4) = st;
}

// ---------------------------------------------------------------------------
// k_qkv R12 (unchanged, champion): LDS weight staging + coalesced epilogue.
// ---------------------------------------------------------------------------
__global__ __launch_bounds__(256) void k_qkv(const float* __restrict__ x,
                                             const u16* __restrict__ wqb,
                                             u16* __restrict__ qkvb) {
  __shared__ u32 tile[8704];   // max(x-stage 128*65, weights 128*68)
  const int tid = threadIdx.x, w = tid >> 6, lane = tid & 63;
  const int c16 = lane & 15, rg = lane >> 4;
  const int b = blockIdx.z;
  const int P0 = blockIdx.x * 128;
  const float* sb = x + (size_t)b * C_ * HW_ + P0;

  #pragma unroll
  for (int ci = 0; ci < 4; ++ci) {
    int cp = 16 * w + 4 * ci + rg;
    #pragma unroll
    for (int ph = 0; ph < 2; ++ph) {
      int p = 4 * c16 + 64 * ph;
      const float* r0 = sb + (size_t)(2 * cp) * HW_ + p;
      float4 a  = *(const float4*)r0;
      float4 bb = *(const float4*)(r0 + HW_);
      tile[(p + 0) * 65 + cp] = pk2(a.x, bb.x);
      tile[(p + 1) * 65 + cp] = pk2(a.y, bb.y);
      tile[(p + 2) * 65 + cp] = pk2(a.z, bb.z);
      tile[(p + 3) * 65 + cp] = pk2(a.w, bb.w);
    }
  }
  __syncthreads();

  const int pw = w * 32;
  bf16x8 bfr[2][4];
  #pragma unroll
  for (int nt = 0; nt < 2; ++nt)
    #pragma unroll
    for (int kk = 0; kk < 4; ++kk) {
      int p = pw + nt * 16 + c16;
      int cp0 = kk * 16 + rg * 4;
      union { u32 d[4]; bf16x8 f; } u;
      u.d[0] = tile[p * 65 + cp0];
      u.d[1] = tile[p * 65 + cp0 + 1];
      u.d[2] = tile[p * 65 + cp0 + 2];
      u.d[3] = tile[p * 65 + cp0 + 3];
      bfr[nt][kk] = u.f;
    }
  __syncthreads();   // x-tile dead; region reused for weights + eb

  u32* eb = tile + w * 544;

  const int p0 = P0 + pw;
  const f32x4 zero = {0.f, 0.f, 0.f, 0.f};
  #pragma unroll 1
  for (int pass = 0; pass < 3; ++pass) {
    {
      const u16* wsrc = wqb + (size_t)pass * 16384;
      #pragma unroll
      for (int j = 0; j < 8; ++j) {
        int idx = tid + 256 * j;
        uint4 v = *(const uint4*)(wsrc + idx * 8);
        *(uint4*)(tile + (idx >> 4) * 68 + (idx & 15) * 4) = v;
      }
    }
    __syncthreads();

    f32x4 acc[8][2];
    #pragma unroll
    for (int mt = 0; mt < 8; ++mt) { acc[mt][0] = zero; acc[mt][1] = zero; }

    #pragma unroll
    for (int kk = 0; kk < 4; ++kk) {
      #pragma unroll
      for (int mt = 0; mt < 8; ++mt) {
        union { uint4 u; bf16x8 f; } afu;
        afu.u = *(const uint4*)(tile + (mt * 16 + c16) * 68 + kk * 16 + rg * 4);
        acc[mt][0] = __builtin_amdgcn_mfma_f32_16x16x32_bf16(afu.f, bfr[0][kk], acc[mt][0], 0, 0, 0);
        acc[mt][1] = __builtin_amdgcn_mfma_f32_16x16x32_bf16(afu.f, bfr[1][kk], acc[mt][1], 0, 0, 0);
      }
    }
    __syncthreads();   // all waves' weight reads done before eb overwrites

    u16* ob = qkvb + (size_t)pass * ((size_t)B_ * NH * HW_ * D_);
    #pragma unroll
    for (int h = 0; h < 4; ++h) {
      #pragma unroll
      for (int m2 = 0; m2 < 2; ++m2) {
        #pragma unroll
        for (int nt = 0; nt < 2; ++nt) {
          f32x4 oa = acc[2 * h + m2][nt];
          int pixl = nt * 16 + c16;
          int dp = m2 * 8 + rg * 2;
          eb[pixl * 17 + dp]     = cvtpk(oa[0], oa[1]);
          eb[pixl * 17 + dp + 1] = cvtpk(oa[2], oa[3]);
        }
      }
      #pragma unroll
      for (int s = 0; s < 2; ++s) {
        int pixl = s * 16 + (lane >> 2);
        const u32* src = eb + pixl * 17 + (lane & 3) * 4;
        uint4 v; v.x = src[0]; v.y = src[1]; v.z = src[2]; v.w = src[3];
        *(uint4*)(ob + ((size_t)(b * NH + h) * HW_ + p0 + pixl) * 32 + (lane & 3) * 8) = v;
      }
    }
    __syncthreads();   // eb readbacks done before next pass's weight load
  }
}

// ---------------------------------------------------------------------------
// k_proj R12 (unchanged, champion): LDS weight staging + coalesced epilogue.
// ---------------------------------------------------------------------------
__global__ __launch_bounds__(256) void k_proj(const u16* __restrict__ cv,
                                              const u16* __restrict__ wpb,
                                              float* __restrict__ out) {
  __shared__ u32 tile[8704];
  const int tid = threadIdx.x, w = tid >> 6, lane = tid & 63;
  const int c16 = lane & 15, rg = lane >> 4;
  const int b = blockIdx.z;
  const int P0 = blockIdx.x * 128;
  const u16* sb = cv + (size_t)b * C_ * HW_ + P0;

  #pragma unroll
  for (int ci = 0; ci < 4; ++ci) {
    int cp = 16 * w + 4 * ci + rg;
    #pragma unroll
    for (int ph = 0; ph < 2; ++ph) {
      int p = 4 * c16 + 64 * ph;
      const u16* r0 = sb + (size_t)(2 * cp) * HW_ + p;
      uint2 a  = *(const uint2*)r0;
      uint2 bb = *(const uint2*)(r0 + HW_);
      tile[(p + 0) * 65 + cp] = (a.x & 0xffffu) | (bb.x << 16);
      tile[(p + 1) * 65 + cp] = (a.x >> 16)     | (bb.x & 0xffff0000u);
      tile[(p + 2) * 65 + cp] = (a.y & 0xffffu) | (bb.y << 16);
      tile[(p + 3) * 65 + cp] = (a.y >> 16)     | (bb.y & 0xffff0000u);
    }
  }
  __syncthreads();

  const int pw = w * 32;
  bf16x8 bfr[2][4];
  #pragma unroll
  for (int nt = 0; nt < 2; ++nt)
    #pragma unroll
    for (int kk = 0; kk < 4; ++kk) {
      int p = pw + nt * 16 + c16;
      int cp0 = kk * 16 + rg * 4;
      union { u32 d[4]; bf16x8 f; } u;
      u.d[0] = tile[p * 65 + cp0];
      u.d[1] = tile[p * 65 + cp0 + 1];
      u.d[2] = tile[p * 65 + cp0 + 2];
      u.d[3] = tile[p * 65 + cp0 + 3];
      bfr[nt][kk] = u.f;
    }
  __syncthreads();   // tile dead; reuse for weights + eb

  u32* eb = tile + w * 544;

  #pragma unroll
  for (int j = 0; j < 8; ++j) {
    int idx = tid + 256 * j;
    uint4 v = *(const uint4*)(wpb + idx * 8);
    *(uint4*)(tile + (idx >> 4) * 68 + (idx & 15) * 4) = v;
  }
  __syncthreads();

  const int p0 = P0 + pw;
  const f32x4 zero = {0.f, 0.f, 0.f, 0.f};
  f32x4 acc[8][2];
  #pragma unroll
  for (int mt = 0; mt < 8; ++mt) { acc[mt][0] = zero; acc[mt][1] = zero; }

  #pragma unroll
  for (int kk = 0; kk < 4; ++kk) {
    #pragma unroll
    for (int mt = 0; mt < 8; ++mt) {
      union { uint4 u; bf16x8 f; } afu;
      afu.u = *(const uint4*)(tile + (mt * 16 + c16) * 68 + kk * 16 + rg * 4);
      acc[mt][0] = __builtin_amdgcn_mfma_f32_16x16x32_bf16(afu.f, bfr[0][kk], acc[mt][0], 0, 0, 0);
      acc[mt][1] = __builtin_amdgcn_mfma_f32_16x16x32_bf16(afu.f, bfr[1][kk], acc[mt][1], 0, 0, 0);
    }
  }
  __syncthreads();   // weight reads done before eb overwrites

  float* ob = out + (size_t)b * C_ * HW_;
  #pragma unroll
  for (int mt = 0; mt < 8; ++mt) {
    #pragma unroll
    for (int nt = 0; nt < 2; ++nt) {
      f32x4 oa = acc[mt][nt];
      int pixl = nt * 16 + c16;
      #pragma unroll
      for (int r = 0; r < 4; ++r) {
        union { float f; u32 u; } cu; cu.f = oa[r];
        eb[(rg * 4 + r) * 33 + pixl] = cu.u;
      }
    }
    #pragma unroll
    for (int s = 0; s < 2; ++s) {
      int ol = s * 8 + (lane >> 3);
      int px = (lane & 7) * 4;
      const u32* src = eb + ol * 33 + px;
      uint4 v; v.x = src[0]; v.y = src[1]; v.z = src[2]; v.w = src[3];
      *(uint4*)(ob + (size_t)(mt * 16 + ol) * HW_ + p0 + px) = v;
    }
  }
}

// ---------------------------------------------------------------------------
// k_attn_mfma R16 = byte-exact R13 (proven 62us, VGPR 84 = 6 waves/SIMD).
// R14/R15 post-mortem: the 62->69 regression tracked VGPR 84->96/92 across
// the ~85-VGPR cliff (512/6=85.3); pipeline/chain-break changes were
// irrelevant. RULE: any attn edit must keep VGPR <= 84.
// ---------------------------------------------------------------------------
__global__ __launch_bounds__(256) void k_attn_mfma(const u16* __restrict__ qb,
                                                   const u16* __restrict__ kb,
                                                   const u16* __restrict__ vb,
                                                   const float* __restrict__ gp,
                                                   u16* __restrict__ houtb,
                                                   u16* __restrict__ woutb) {
  __shared__ u32 lds[4][16 * 68 + 32 * 18];
  const int tid  = threadIdx.x;
  const int w    = tid >> 6;
  const int lane = tid & 63;
  const int head = blockIdx.y & 3;
  const int axis = blockIdx.y >> 2;
  const int b    = blockIdx.z;
  const int line = blockIdx.x * 4 + w;
  u32* vt = &lds[w][0];
  u32* pt = &lds[w][0];          // alias: vt dead after vf frags resident
  u32* ot = &lds[w][16 * 68];    // output staging tile [32 d][18 dw]
  const size_t base = (size_t)(b * NH + head) * HW_ * D_;
  const float g = gp[0];
  const int c16 = lane & 15, rg = lane >> 4;
  const size_t pstride = axis ? (size_t)128 * D_ : (size_t)D_;
  const size_t lbase   = base + (size_t)line * (axis ? D_ : 128 * D_);

  u32 v0r[16], v1r[16];
  {
    const u16* v0p = vb + lbase + (size_t)(2 * lane) * pstride;
    const u16* v1p = v0p + pstride;
    #pragma unroll
    for (int t = 0; t < 4; ++t) {
      *(uint4*)&v0r[4 * t] = *(const uint4*)(v0p + 8 * t);
      *(uint4*)&v1r[4 * t] = *(const uint4*)(v1p + 8 * t);
    }
  }

  bf16x8 kf[8];
  #pragma unroll
  for (int nt = 0; nt < 8; ++nt)
    kf[nt] = ld_frag_g(kb + lbase + (size_t)(nt * 16 + c16) * pstride + rg * 8);

  bf16x8 vf[2][4];
  #pragma unroll
  for (int ph = 0; ph < 2; ++ph) {
    #pragma unroll
    for (int dw = 0; dw < 8; ++dw) {
      u32 a = v0r[ph * 8 + dw], bq = v1r[ph * 8 + dw];
      u32 lo = (a & 0xffffu) | (bq << 16);
      u32 hi = (a >> 16) | (bq & 0xffff0000u);
      vt[(2 * dw) * 68 + lane]     = lo;
      vt[(2 * dw + 1) * 68 + lane] = hi;
    }
    #pragma unroll
    for (int t = 0; t < 4; ++t) {
      union { uint4 u; bf16x8 f; } c;
      c.u = *(const uint4*)(vt + c16 * 68 + t * 16 + rg * 4);
      vf[ph][t] = c.f;
    }
  }

  const float R1v  = __expf(-g),        Ri1v  = __expf(g);
  const float R12v = __expf(-12.f * g), Ri12v = __expf(12.f * g);
  const float R16v = __expf(-16.f * g), Ri16v = __expf(16.f * g);
  const f32x2 R1p   = {R1v,  Ri1v};
  const f32x2 R12p  = {R12v, Ri12v};
  const f32x2 R16ip = {Ri16v, R16v};
  float t0 = (float)(rg * 4 - c16);
  f32x2 F2 = {__expf(-g * t0), __expf(g * t0)};

  u16* ob = axis ? woutb : houtb;
  const f32x4 zero = {0.f, 0.f, 0.f, 0.f};

  bf16x8 qf = ld_frag_g(qb + lbase + (size_t)c16 * pstride + rg * 8);

  #pragma unroll 1
  for (int mt = 0; mt < 8; ++mt) {
    int mtn = mt < 7 ? mt + 1 : 7;
    bf16x8 qf_n = ld_frag_g(qb + lbase + (size_t)(mtn * 16 + c16) * pstride + rg * 8);

    f32x4 sa[8];
    __builtin_amdgcn_s_setprio(1);
    #pragma unroll
    for (int nt = 0; nt < 8; ++nt)
      sa[nt] = __builtin_amdgcn_mfma_f32_16x16x32_bf16(kf[nt], qf, zero, 0, 0, 0);
    __builtin_amdgcn_s_setprio(0);

    f32x2 l2 = {0.f, 0.f};
    #pragma unroll
    for (int nt = 0; nt < 8; ++nt) {
      f32x4 s4 = sa[nt] * SCL2E;
      float e0 = __builtin_amdgcn_exp2f(s4[0]);
      float e1 = __builtin_amdgcn_exp2f(s4[1]);
      float e2 = __builtin_amdgcn_exp2f(s4[2]);
      float e3 = __builtin_amdgcn_exp2f(s4[3]);
      sa[nt][0] = e0; sa[nt][1] = e1; sa[nt][2] = e2; sa[nt][3] = e3;
      l2 += (f32x2){e0, e1};
      l2 += (f32x2){e2, e3};
    }
    float l = l2[0] + l2[1];
    l += __shfl_xor(l, 16);
    l += __shfl_xor(l, 32);
    float linv = __builtin_amdgcn_rcpf(l);

    f32x2 ffi = F2 * linv;
    #pragma unroll
    for (int nt = 0; nt < 8; ++nt) {
      float d0 = fminf(ffi[0], ffi[1]); ffi *= R1p;
      float d1 = fminf(ffi[0], ffi[1]); ffi *= R1p;
      float d2 = fminf(ffi[0], ffi[1]); ffi *= R1p;
      float d3 = fminf(ffi[0], ffi[1]); ffi *= R1p;
      ffi *= R12p;
      f32x2 p01 = (f32x2){sa[nt][0], sa[nt][1]} * (f32x2){d0, d1};
      f32x2 p23 = (f32x2){sa[nt][2], sa[nt][3]} * (f32x2){d2, d3};
      uint2 st;
      st.x = cvtpk(p01[0], p01[1]);
      st.y = cvtpk(p23[0], p23[1]);
      *(uint2*)(pt + c16 * 68 + nt * 8 + rg * 2) = st;
    }
    F2 *= R16ip;

    f32x4 oa0 = zero, oa1 = zero;
    __builtin_amdgcn_s_setprio(1);
    #pragma unroll
    for (int t = 0; t < 4; ++t) {
      union { uint4 u; bf16x8 f; } af;
      af.u = *(const uint4*)(pt + c16 * 68 + t * 16 + rg * 4);
      oa0 = __builtin_amdgcn_mfma_f32_16x16x32_bf16(af.f, vf[0][t], oa0, 0, 0, 0);
      oa1 = __builtin_amdgcn_mfma_f32_16x16x32_bf16(af.f, vf[1][t], oa1, 0, 0, 0);
    }
    __builtin_amdgcn_s_setprio(0);

    {
      int mo = mt & 1;
      uint2 st0, st1;
      st0.x = cvtpk(oa0[0], oa0[1]); st0.y = cvtpk(oa0[2], oa0[3]);
      st1.x = cvtpk(oa1[0], oa1[1]); st1.y = cvtpk(oa1[2], oa1[3]);
      *(uint2*)(ot + c16 * 18 + mo * 8 + rg * 2)        = st0;
      *(uint2*)(ot + (16 + c16) * 18 + mo * 8 + rg * 2) = st1;
      if (mo) {
        int zb = (mt >> 1) * 32;
        int q = lane & 3;
        #pragma unroll
        for (int s = 0; s < 2; ++s) {
          int d = s * 16 + (lane >> 2);
          const u32* src = ot + d * 18 + q * 4;
          uint4 v; v.x = src[0]; v.y = src[1]; v.z = src[2]; v.w = src[3];
          *(uint4*)(ob + ((size_t)(b * C_ + head * D_ + d) * 128 + line) * 128 + zb + q * 8) = v;
        }
      }
    }
    qf = qf_n;
  }
}

// ---------------------------------------------------------------------------
// k_conv R14 (unchanged, champion): conflict-free transpose-add + vectorized
// 8-pixel stencil with coalesced uint4 stores.
// ---------------------------------------------------------------------------
__global__ __launch_bounds__(256) void k_conv(const u16* __restrict__ hb,
                                              const u16* __restrict__ wb,
                                              const float* __restrict__ wdw,
                                              u16* __restrict__ convo) {
  __shared__ u16 t[128 * 136];
  const int tid = threadIdx.x;
  const int c = blockIdx.x, b = blockIdx.y;
  const size_t pb = (size_t)(b * C_ + c) * HW_;

  for (int i = tid; i < 2048; i += 256) {
    int e = i * 8; int r = e >> 7, col = e & 127;
    *(uint4*)&t[r * 136 + col] = *(const uint4*)(hb + pb + e);
  }
  __syncthreads();

  {
    const int p = tid & 63;
    const int hc0 = (tid >> 6) * 32;
    u32* tw = (u32*)t;
    u32 w0[16], w1[16];
    const u16* r0 = wb + pb + (size_t)(2 * p) * 128 + hc0;
    const u16* r1 = r0 + 128;
    #pragma unroll
    for (int q = 0; q < 4; ++q) {
      *(uint4*)&w0[4 * q] = *(const uint4*)(r0 + 8 * q);
      *(uint4*)&w1[4 * q] = *(const uint4*)(r1 + 8 * q);
    }
    #pragma unroll
    for (int k = 0; k < 32; ++k) {
      u32 d = tw[(hc0 + k) * 68 + p];
      u32 wa = (k & 1) ? (w0[k >> 1] & 0xffff0000u) : (w0[k >> 1] << 16);
      u32 wc = (k & 1) ? (w1[k >> 1] & 0xffff0000u) : (w1[k >> 1] << 16);
      union { u32 u; float f; } fa, fc;
      fa.u = wa; fc.u = wc;
      f32x2 s = (f32x2){bflo(d) + fa.f, bfhi(d) + fc.f};
      tw[(hc0 + k) * 68 + p] = cvtpk(s[0], s[1]);
    }
  }
  __syncthreads();

  float k9[9];
  #pragma unroll
  for (int i = 0; i < 9; ++i) k9[i] = wdw[c * 9 + i];

  for (int ch = tid; ch < 2048; ch += 256) {
    int r = ch >> 4;
    int c0 = (ch & 15) << 3;
    float a0 = 0.f, a1 = 0.f, a2 = 0.f, a3 = 0.f;
    float a4 = 0.f, a5 = 0.f, a6 = 0.f, a7 = 0.f;
    #pragma unroll
    for (int di = 0; di < 3; ++di) {
      int rr = r + di - 1;
      if (rr < 0 || rr > 127) continue;
      const u16* row = &t[rr * 136 + c0];
      union { uint4 u; u16 h[8]; } m;
      m.u = *(const uint4*)row;
      float v0 = c0 ? bf2f_u(row[-1]) : 0.f;
      float v1 = bf2f_u(m.h[0]), v2 = bf2f_u(m.h[1]), v3 = bf2f_u(m.h[2]);
      float v4 = bf2f_u(m.h[3]), v5 = bf2f_u(m.h[4]), v6 = bf2f_u(m.h[5]);
      float v7 = bf2f_u(m.h[6]), v8 = bf2f_u(m.h[7]);
      float v9 = (c0 < 120) ? bf2f_u(row[8]) : 0.f;
      float ka = k9[di * 3], kb2 = k9[di * 3 + 1], kc = k9[di * 3 + 2];
      a0 += ka * v0 + kb2 * v1 + kc * v2;
      a1 += ka * v1 + kb2 * v2 + kc * v3;
      a2 += ka * v2 + kb2 * v3 + kc * v4;
      a3 += ka * v3 + kb2 * v4 + kc * v5;
      a4 += ka * v4 + kb2 * v5 + kc * v6;
      a5 += ka * v5 + kb2 * v6 + kc * v7;
      a6 += ka * v6 + kb2 * v7 + kc * v8;
      a7 += ka * v7 + kb2 * v8 + kc * v9;
    }
    uint4 st;
    st.x = cvtpk(a0, a1); st.y = cvtpk(a2, a3);
    st.z = cvtpk(a4, a5); st.w = cvtpk(a6, a7);
    *(uint4*)(convo + pb + r * 128 + c0) = st;
  }
}

// ---------------------------------------------------------------------------
extern "C" void kernel_launch(void* const* d_in, const int* in_sizes, int n_in,
                              void* d_out, int out_size, void* d_ws, size_t ws_size,
                              hipStream_t stream) {
  const float* x     = (const float*)d_in[0];
  const float* wqkv  = (const float*)d_in[1];
  const float* wproj = (const float*)d_in[2];
  const float* wdw   = (const float*)d_in[3];
  const float* gamma = (const float*)d_in[4];
  float* out = (float*)d_out;
  char* ws = (char*)d_ws;

  u16* q   = (u16*)(ws);                    // 32 MB [B,4,HW,32] bf16
  u16* k   = (u16*)(ws + 33554432ull);      // 32 MB
  u16* v   = (u16*)(ws + 67108864ull);      // 32 MB
  u16* hb  = (u16*)(ws + 100663296ull);     // 32 MB [B,C,H,W] bf16 (attn-H out)
  u16* wb  = (u16*)(ws + 134217728ull);     // 32 MB [B,C,W,H] bf16 (attn-W out)
  u16* cv  = (u16*)(ws + 167772160ull);     // 32 MB [B,C,HW] bf16 (conv out)
  u16* wqb = (u16*)(ws + 201326592ull);     // 96 KB bf16 qkv weights
  u16* wpb = (u16*)(ws + 201326592ull + 131072ull); // 32 KB bf16 proj weights

  k_wcvt2    <<<dim3(64),        256, 0, stream>>>(wqkv, wproj, wqb, wpb);
  k_qkv      <<<dim3(128, 1, 8), 256, 0, stream>>>(x, wqb, q);
  k_attn_mfma<<<dim3(32, 8, 8),  256, 0, stream>>>(q, k, v, gamma, hb, wb);
  k_conv     <<<dim3(128, 8),    256, 0, stream>>>(hb, wb, wdw, cv);
  k_proj     <<<dim3(128, 1, 8), 256, 0, stream>>>(cv, wpb, out);
}